// Round 2
// baseline (1076.465 us; speedup 1.0000x reference)
//
#include <hip/hip_runtime.h>
#include <cstdint>
#include <cstddef>

// MultiHeadSelfAttention: B=4 H=16 S=2048 D=1024 d=64
// d_out = [output fp32 (4,2048,1024)] ++ [attn_weights fp32 (4,16,2048,2048)]
//
// R2: swapped-operand QK^T (mfma(K,Q)) -> lane-local softmax reductions,
// float4 attn-weight stores, 8B P->LDS staging. GEMMs unchanged from R1.

#define D_MODEL 1024
#define NHEADS  16
#define HDIM    64
#define BATCH   4
#define SEQ     2048
#define NTOK    (BATCH*SEQ)   // 8192

typedef __bf16 bf16x8 __attribute__((ext_vector_type(8)));
typedef float  f32x4  __attribute__((ext_vector_type(4)));
typedef unsigned short u16x8 __attribute__((ext_vector_type(8)));

__device__ __forceinline__ uint16_t f2bf(float f) {
  union { float f; uint32_t u; } v; v.f = f;
  return (uint16_t)((v.u + 0x7FFFu + ((v.u >> 16) & 1u)) >> 16);
}
__device__ __forceinline__ bf16x8 ldbf8(const uint16_t* p) {
  return __builtin_bit_cast(bf16x8, *(const u16x8*)p);
}

// ---------------- fp32 -> bf16 convert ----------------
__global__ __launch_bounds__(256) void cvt_kernel(const float* __restrict__ src,
                                                  uint16_t* __restrict__ dst, int n4) {
  int i = blockIdx.x * blockDim.x + threadIdx.x;
  if (i < n4) {
    float4 f = ((const float4*)src)[i];
    ushort4 o;
    o.x = f2bf(f.x); o.y = f2bf(f.y); o.z = f2bf(f.z); o.w = f2bf(f.w);
    ((ushort4*)dst)[i] = o;
  }
}

// ---------------- GEMM: out[m,n] = sum_k A[m,k]*Bt[n,k] + bias[n] ----------------
// A: [M,K] bf16 row-major; Bt: [N,K] bf16 row-major (i.e. W, used as x@W^T).
// MODE 0: out bf16 [M,N]. MODE 1: out bf16 V^T per head: [(b,h,d),s].
// MODE 2: out fp32 [M,N].
template <int MODE>
__global__ __launch_bounds__(256)
void gemm_bt(const uint16_t* __restrict__ A, const uint16_t* __restrict__ Bt,
             const float* __restrict__ bias, void* __restrict__ out,
             int M, int N, int K) {
  __shared__ uint16_t As[128 * 72];
  __shared__ uint16_t Bs[128 * 72];
  const int tid  = threadIdx.x;
  const int lane = tid & 63;
  const int wave = tid >> 6;
  const int wr = wave >> 1, wc = wave & 1;
  const int m0 = blockIdx.y * 128, n0 = blockIdx.x * 128;
  const int lrow = lane & 15;
  const int lk8  = (lane >> 4) * 8;

  f32x4 acc[4][4] = {};

  for (int k0 = 0; k0 < K; k0 += 64) {
#pragma unroll
    for (int it = 0; it < 4; ++it) {
      int c = tid + it * 256;
      int row = c >> 3, kc = (c & 7) * 8;
      *(u16x8*)&As[row * 72 + kc] = *(const u16x8*)&A [(size_t)(m0 + row) * K + k0 + kc];
      *(u16x8*)&Bs[row * 72 + kc] = *(const u16x8*)&Bt[(size_t)(n0 + row) * K + k0 + kc];
    }
    __syncthreads();
#pragma unroll
    for (int ks = 0; ks < 2; ++ks) {
      bf16x8 af[4], bfr[4];
#pragma unroll
      for (int i = 0; i < 4; ++i) {
        af [i] = ldbf8(&As[(wr * 64 + i * 16 + lrow) * 72 + ks * 32 + lk8]);
        bfr[i] = ldbf8(&Bs[(wc * 64 + i * 16 + lrow) * 72 + ks * 32 + lk8]);
      }
#pragma unroll
      for (int i = 0; i < 4; ++i)
#pragma unroll
        for (int j = 0; j < 4; ++j)
          acc[i][j] = __builtin_amdgcn_mfma_f32_16x16x32_bf16(af[i], bfr[j], acc[i][j], 0, 0, 0);
    }
    __syncthreads();
  }

  const int r0 = (lane >> 4) * 4;
#pragma unroll
  for (int i = 0; i < 4; ++i) {
#pragma unroll
    for (int j = 0; j < 4; ++j) {
      int gmb = m0 + wr * 64 + i * 16 + r0;
      int gn  = n0 + wc * 64 + j * 16 + lrow;
      float bv = bias[gn];
#pragma unroll
      for (int r = 0; r < 4; ++r) {
        float v = acc[i][j][r] + bv;
        int gm = gmb + r;
        if (MODE == 0) {
          ((uint16_t*)out)[(size_t)gm * N + gn] = f2bf(v);
        } else if (MODE == 1) {
          int b = gm >> 11, s = gm & (SEQ - 1);
          int h = gn >> 6,  d = gn & (HDIM - 1);
          ((uint16_t*)out)[(((size_t)(b * NHEADS + h) * HDIM + d) << 11) + s] = f2bf(v);
        } else {
          ((float*)out)[(size_t)gm * N + gn] = v;
        }
      }
    }
  }
}

// ---------------- Attention (swapped-operand QK^T) ----------------
// grid (S/64, H, B), 256 thr = 4 waves; wave handles 16 q rows.
// mfma(K,Q) -> D[row=k_local, col=q_local]: lane holds 4 k-consecutive scores
// for q = lane&15. Softmax state (m,l) is lane-local; combine via 2 shfl at end.
__global__ __launch_bounds__(256)
void attn_kernel(const uint16_t* __restrict__ Q, const uint16_t* __restrict__ Kb,
                 const uint16_t* __restrict__ Vt, float* __restrict__ attnw,
                 uint16_t* __restrict__ ctx) {
  __shared__ uint16_t plds[4][16][36];   // per-wave P tile, row stride 72B
  const int tid  = threadIdx.x;
  const int lane = tid & 63;
  const int wave = tid >> 6;
  const int qt = blockIdx.x, h = blockIdx.y, b = blockIdx.z;
  const int q0 = qt * 64 + wave * 16;
  const int lrow = lane & 15;          // q_local (QK out) / k-row (K frag)
  const int grp  = lane >> 4;
  const int lk8  = grp * 8;
  const float c = 0.125f * 1.44269504088896f;  // (1/sqrt(64)) * log2(e)

  const size_t qbase = ((size_t)(b * SEQ) + q0 + lrow) * D_MODEL + h * HDIM;
  const bf16x8 qf0 = ldbf8(&Q[qbase + lk8]);
  const bf16x8 qf1 = ldbf8(&Q[qbase + 32 + lk8]);

  const uint16_t* Kh = Kb + (size_t)(b * SEQ) * D_MODEL + h * HDIM;   // K[s][d]
  const uint16_t* Vh = Vt + ((size_t)(b * NHEADS + h) * HDIM) * SEQ;  // V^T[d][s]

  // ---- pass A: lane-local online max+sum (log2 domain) ----
  float m = -INFINITY, l = 0.f;
#pragma unroll 2
  for (int kt = 0; kt < SEQ / 16; ++kt) {
    const size_t kb = (size_t)(kt * 16 + lrow) * D_MODEL + lk8;
    f32x4 s = {};
    s = __builtin_amdgcn_mfma_f32_16x16x32_bf16(ldbf8(&Kh[kb]),      qf0, s, 0, 0, 0);
    s = __builtin_amdgcn_mfma_f32_16x16x32_bf16(ldbf8(&Kh[kb + 32]), qf1, s, 0, 0, 0);
    float v0 = s[0] * c, v1 = s[1] * c, v2 = s[2] * c, v3 = s[3] * c;
    float m4 = fmaxf(fmaxf(v0, v1), fmaxf(v2, v3));
    float mn = fmaxf(m, m4);
    l = l * __builtin_amdgcn_exp2f(m - mn)
      + __builtin_amdgcn_exp2f(v0 - mn) + __builtin_amdgcn_exp2f(v1 - mn)
      + __builtin_amdgcn_exp2f(v2 - mn) + __builtin_amdgcn_exp2f(v3 - mn);
    m = mn;
  }
  // combine the 4 lane-groups (each covered k%16 in [4g,4g+4))
#pragma unroll
  for (int d = 16; d <= 32; d <<= 1) {
    float mp = __shfl_xor(m, d), lp = __shfl_xor(l, d);
    float mn = fmaxf(m, mp);
    l = l * __builtin_amdgcn_exp2f(m - mn) + lp * __builtin_amdgcn_exp2f(mp - mn);
    m = mn;
  }
  const float rinv = 1.0f / l;

  // ---- pass B: recompute scores, write weights, PV ----
  f32x4 cacc[4] = {};
  float* aw = attnw + (((size_t)(b * NHEADS + h)) * SEQ + q0 + lrow) * SEQ;  // row q=lrow
  for (int kc = 0; kc < SEQ / 32; ++kc) {
    const int kbase = kc * 32;
    const size_t kb0 = (size_t)(kbase + lrow) * D_MODEL + lk8;
    const size_t kb1 = kb0 + (size_t)16 * D_MODEL;
    f32x4 s0 = {}, s1 = {};
    s0 = __builtin_amdgcn_mfma_f32_16x16x32_bf16(ldbf8(&Kh[kb0]),      qf0, s0, 0, 0, 0);
    s0 = __builtin_amdgcn_mfma_f32_16x16x32_bf16(ldbf8(&Kh[kb0 + 32]), qf1, s0, 0, 0, 0);
    s1 = __builtin_amdgcn_mfma_f32_16x16x32_bf16(ldbf8(&Kh[kb1]),      qf0, s1, 0, 0, 0);
    s1 = __builtin_amdgcn_mfma_f32_16x16x32_bf16(ldbf8(&Kh[kb1 + 32]), qf1, s1, 0, 0, 0);

    float p0[4], p1[4];
#pragma unroll
    for (int r = 0; r < 4; ++r) {
      p0[r] = __builtin_amdgcn_exp2f(s0[r] * c - m) * rinv;
      p1[r] = __builtin_amdgcn_exp2f(s1[r] * c - m) * rinv;
    }
    // attn weights: lane's q row, 4 consecutive k each -> float4 stores
    *(float4*)&aw[kbase + grp * 4]      = make_float4(p0[0], p0[1], p0[2], p0[3]);
    *(float4*)&aw[kbase + 16 + grp * 4] = make_float4(p1[0], p1[1], p1[2], p1[3]);
    // stage P (bf16) for the PV A-fragment: row=q_local, cols k_local
    ushort4 w0, w1;
    w0.x = f2bf(p0[0]); w0.y = f2bf(p0[1]); w0.z = f2bf(p0[2]); w0.w = f2bf(p0[3]);
    w1.x = f2bf(p1[0]); w1.y = f2bf(p1[1]); w1.z = f2bf(p1[2]); w1.w = f2bf(p1[3]);
    *(ushort4*)&plds[wave][lrow][grp * 4]      = w0;
    *(ushort4*)&plds[wave][lrow][16 + grp * 4] = w1;
    asm volatile("s_waitcnt lgkmcnt(0)" ::: "memory");
    const bf16x8 pf = ldbf8(&plds[wave][lrow][lk8]);  // A-frag: row=q_local
#pragma unroll
    for (int n = 0; n < 4; ++n) {
      const bf16x8 vf = ldbf8(&Vh[(size_t)(n * 16 + lrow) * SEQ + kbase + lk8]);
      cacc[n] = __builtin_amdgcn_mfma_f32_16x16x32_bf16(pf, vf, cacc[n], 0, 0, 0);
    }
  }
  // ctx: D[row=q_local=grp*4+r, col=d_local=n*16+lrow]
#pragma unroll
  for (int n = 0; n < 4; ++n)
#pragma unroll
    for (int r = 0; r < 4; ++r) {
      int gq = q0 + grp * 4 + r;
      ctx[((size_t)(b * SEQ) + gq) * D_MODEL + h * HDIM + n * 16 + lrow] = f2bf(cacc[n][r]);
    }
}

// ---------------- launch ----------------
extern "C" void kernel_launch(void* const* d_in, const int* in_sizes, int n_in,
                              void* d_out, int out_size, void* d_ws, size_t ws_size,
                              hipStream_t stream) {
  const float* x  = (const float*)d_in[0];
  const float* wq = (const float*)d_in[1];
  const float* bq = (const float*)d_in[2];
  const float* wk = (const float*)d_in[3];
  const float* bk = (const float*)d_in[4];
  const float* wv = (const float*)d_in[5];
  const float* bv = (const float*)d_in[6];
  const float* wo = (const float*)d_in[7];
  const float* bo = (const float*)d_in[8];

  char* ws = (char*)d_ws;
  uint16_t* xb  = (uint16_t*)ws;                      // 16 MB (reused as ctx later)
  uint16_t* wqb = (uint16_t*)(ws + (16u << 20));
  uint16_t* wkb = (uint16_t*)(ws + (18u << 20));
  uint16_t* wvb = (uint16_t*)(ws + (20u << 20));
  uint16_t* wob = (uint16_t*)(ws + (22u << 20));
  uint16_t* Qb  = (uint16_t*)(ws + (24u << 20));
  uint16_t* Kc  = (uint16_t*)(ws + (40u << 20));
  uint16_t* Vtb = (uint16_t*)(ws + (56u << 20));
  uint16_t* ctx = xb;

  float* outp  = (float*)d_out;
  float* attnw = outp + (size_t)NTOK * D_MODEL;

  {
    int n4 = (NTOK * D_MODEL) / 4;
    cvt_kernel<<<(n4 + 255) / 256, 256, 0, stream>>>(x, xb, n4);
    int w4 = (D_MODEL * D_MODEL) / 4;
    cvt_kernel<<<(w4 + 255) / 256, 256, 0, stream>>>(wq, wqb, w4);
    cvt_kernel<<<(w4 + 255) / 256, 256, 0, stream>>>(wk, wkb, w4);
    cvt_kernel<<<(w4 + 255) / 256, 256, 0, stream>>>(wv, wvb, w4);
    cvt_kernel<<<(w4 + 255) / 256, 256, 0, stream>>>(wo, wob, w4);
  }

  dim3 ggrid(D_MODEL / 128, NTOK / 128);  // (8, 64)
  gemm_bt<0><<<ggrid, 256, 0, stream>>>(xb, wqb, bq, (void*)Qb,  NTOK, D_MODEL, D_MODEL);
  gemm_bt<0><<<ggrid, 256, 0, stream>>>(xb, wkb, bk, (void*)Kc,  NTOK, D_MODEL, D_MODEL);
  gemm_bt<1><<<ggrid, 256, 0, stream>>>(xb, wvb, bv, (void*)Vtb, NTOK, D_MODEL, D_MODEL);

  dim3 agrid(SEQ / 64, NHEADS, BATCH);    // (32, 16, 4)
  attn_kernel<<<agrid, 256, 0, stream>>>(Qb, Kc, Vtb, attnw, ctx);

  gemm_bt<2><<<ggrid, 256, 0, stream>>>(ctx, wob, bo, (void*)outp, NTOK, D_MODEL, D_MODEL);
}

// Round 3
// 518.857 us; speedup vs baseline: 2.0747x; 2.0747x over previous
//
#include <hip/hip_runtime.h>
#include <cstdint>
#include <cstddef>

// MultiHeadSelfAttention: B=4 H=16 S=2048 D=1024 d=64
// d_out = [output fp32 (4,2048,1024)] ++ [attn_weights fp32 (4,16,2048,2048)]
//
// R3: attention rebuilt around LDS staging. K/V staged per 64-key chunk with
// XOR-swizzled layout (coalesced global loads, conflict-floor ds_reads);
// P tile staged per chunk in LDS -> PV fragments AND coalesced fp32 weight
// stores (4 rows x 256B per instr). Pass A double-buffers K.

#define D_MODEL 1024
#define NHEADS  16
#define HDIM    64
#define BATCH   4
#define SEQ     2048
#define NTOK    (BATCH*SEQ)   // 8192

typedef __bf16 bf16x8 __attribute__((ext_vector_type(8)));
typedef float  f32x4  __attribute__((ext_vector_type(4)));
typedef unsigned short u16x8 __attribute__((ext_vector_type(8)));

__device__ __forceinline__ uint16_t f2bf(float f) {
  union { float f; uint32_t u; } v; v.f = f;
  return (uint16_t)((v.u + 0x7FFFu + ((v.u >> 16) & 1u)) >> 16);
}
__device__ __forceinline__ float bf2f(uint16_t u) {
  union { uint32_t u; float f; } v; v.u = (uint32_t)u << 16; return v.f;
}
__device__ __forceinline__ bf16x8 ldbf8(const uint16_t* p) {
  return __builtin_bit_cast(bf16x8, *(const u16x8*)p);
}

// ---------------- fp32 -> bf16 convert ----------------
__global__ __launch_bounds__(256) void cvt_kernel(const float* __restrict__ src,
                                                  uint16_t* __restrict__ dst, int n4) {
  int i = blockIdx.x * blockDim.x + threadIdx.x;
  if (i < n4) {
    float4 f = ((const float4*)src)[i];
    ushort4 o;
    o.x = f2bf(f.x); o.y = f2bf(f.y); o.z = f2bf(f.z); o.w = f2bf(f.w);
    ((ushort4*)dst)[i] = o;
  }
}

// ---------------- GEMM: out[m,n] = sum_k A[m,k]*Bt[n,k] + bias[n] ----------------
template <int MODE>
__global__ __launch_bounds__(256)
void gemm_bt(const uint16_t* __restrict__ A, const uint16_t* __restrict__ Bt,
             const float* __restrict__ bias, void* __restrict__ out,
             int M, int N, int K) {
  __shared__ uint16_t As[128 * 72];
  __shared__ uint16_t Bs[128 * 72];
  const int tid  = threadIdx.x;
  const int lane = tid & 63;
  const int wave = tid >> 6;
  const int wr = wave >> 1, wc = wave & 1;
  const int m0 = blockIdx.y * 128, n0 = blockIdx.x * 128;
  const int lrow = lane & 15;
  const int lk8  = (lane >> 4) * 8;

  f32x4 acc[4][4] = {};

  for (int k0 = 0; k0 < K; k0 += 64) {
#pragma unroll
    for (int it = 0; it < 4; ++it) {
      int c = tid + it * 256;
      int row = c >> 3, kc = (c & 7) * 8;
      *(u16x8*)&As[row * 72 + kc] = *(const u16x8*)&A [(size_t)(m0 + row) * K + k0 + kc];
      *(u16x8*)&Bs[row * 72 + kc] = *(const u16x8*)&Bt[(size_t)(n0 + row) * K + k0 + kc];
    }
    __syncthreads();
#pragma unroll
    for (int ks = 0; ks < 2; ++ks) {
      bf16x8 af[4], bfr[4];
#pragma unroll
      for (int i = 0; i < 4; ++i) {
        af [i] = ldbf8(&As[(wr * 64 + i * 16 + lrow) * 72 + ks * 32 + lk8]);
        bfr[i] = ldbf8(&Bs[(wc * 64 + i * 16 + lrow) * 72 + ks * 32 + lk8]);
      }
#pragma unroll
      for (int i = 0; i < 4; ++i)
#pragma unroll
        for (int j = 0; j < 4; ++j)
          acc[i][j] = __builtin_amdgcn_mfma_f32_16x16x32_bf16(af[i], bfr[j], acc[i][j], 0, 0, 0);
    }
    __syncthreads();
  }

  const int r0 = (lane >> 4) * 4;
#pragma unroll
  for (int i = 0; i < 4; ++i) {
#pragma unroll
    for (int j = 0; j < 4; ++j) {
      int gmb = m0 + wr * 64 + i * 16 + r0;
      int gn  = n0 + wc * 64 + j * 16 + lrow;
      float bv = bias[gn];
#pragma unroll
      for (int r = 0; r < 4; ++r) {
        float v = acc[i][j][r] + bv;
        int gm = gmb + r;
        if (MODE == 0) {
          ((uint16_t*)out)[(size_t)gm * N + gn] = f2bf(v);
        } else if (MODE == 1) {
          int b = gm >> 11, s = gm & (SEQ - 1);
          int h = gn >> 6,  d = gn & (HDIM - 1);
          ((uint16_t*)out)[(((size_t)(b * NHEADS + h) * HDIM + d) << 11) + s] = f2bf(v);
        } else {
          ((float*)out)[(size_t)gm * N + gn] = v;
        }
      }
    }
  }
}

// ---------------- Attention ----------------
// Stage a 64-row x 64-col bf16 tile into LDS with XOR swizzle:
// element (row, col) -> lds[row*64 + ((col/8) ^ (row&7))*8 + col%8]
// Global loads: 8 threads per row = 128B contiguous per 8 lanes.
__device__ __forceinline__ void stage64(uint16_t* __restrict__ dst,
                                        const uint16_t* __restrict__ src,
                                        int sstride, int tid) {
  int r0 = tid >> 3, c0 = tid & 7;
  u16x8 a = *(const u16x8*)&src[(size_t)r0 * sstride + c0 * 8];
  u16x8 b = *(const u16x8*)&src[(size_t)(r0 + 32) * sstride + c0 * 8];
  *(u16x8*)&dst[r0 * 64 + ((c0 ^ (r0 & 7)) * 8)] = a;
  *(u16x8*)&dst[(r0 + 32) * 64 + ((c0 ^ ((r0 + 32) & 7)) * 8)] = b;
}
__device__ __forceinline__ bf16x8 rd_tile(const uint16_t* t, int r, int s) {
  return ldbf8(&t[r * 64 + ((s ^ (r & 7)) * 8)]);
}

// grid (S/64, H, B), 256 thr = 4 waves; wave handles 16 q rows.
// mfma(K,Q): lane holds scores for q=lane&15, k_loc=(lane>>4)*4+r.
__global__ __launch_bounds__(256)
void attn_kernel(const uint16_t* __restrict__ Q, const uint16_t* __restrict__ Kb,
                 const uint16_t* __restrict__ Vt, float* __restrict__ attnw,
                 uint16_t* __restrict__ ctx) {
  __shared__ uint16_t Ks[64 * 64];
  __shared__ uint16_t Vs[64 * 64];
  __shared__ uint16_t Pl[4][16 * 72];   // per-wave P chunk: 16 q x 64 k, pad 8
  const int tid  = threadIdx.x;
  const int lane = tid & 63;
  const int wave = tid >> 6;
  const int qt = blockIdx.x, h = blockIdx.y, b = blockIdx.z;
  const int q0 = qt * 64 + wave * 16;
  const int lrow = lane & 15;
  const int grp  = lane >> 4;
  const float c = 0.125f * 1.44269504088896f;  // (1/sqrt(64)) * log2(e)

  const size_t qbase = ((size_t)(b * SEQ) + q0 + lrow) * D_MODEL + h * HDIM;
  const bf16x8 qf0 = ldbf8(&Q[qbase + grp * 8]);
  const bf16x8 qf1 = ldbf8(&Q[qbase + 32 + grp * 8]);

  const uint16_t* Kh = Kb + (size_t)(b * SEQ) * D_MODEL + h * HDIM;   // [s][d] stride 1024
  const uint16_t* Vh = Vt + ((size_t)(b * NHEADS + h) * HDIM) * SEQ;  // [d][s] stride 2048

  // ---- pass A: online max+sum; K double-buffered (Ks/Vs alternate) ----
  float m = -INFINITY, l = 0.f;
  stage64(Ks, Kh, D_MODEL, tid);
#pragma unroll 1
  for (int kc = 0; kc < SEQ / 64; ++kc) {
    const uint16_t* cur = (kc & 1) ? Vs : Ks;
    uint16_t*       nxt = (kc & 1) ? Ks : Vs;
    __syncthreads();  // cur staged; previous chunk's readers of nxt are done
    if (kc + 1 < SEQ / 64) stage64(nxt, Kh + (size_t)(kc + 1) * 64 * D_MODEL, D_MODEL, tid);
    f32x4 s[4];
#pragma unroll
    for (int kt = 0; kt < 4; ++kt) {
      f32x4 a = {};
      a = __builtin_amdgcn_mfma_f32_16x16x32_bf16(rd_tile(cur, kt * 16 + lrow, grp),     qf0, a, 0, 0, 0);
      a = __builtin_amdgcn_mfma_f32_16x16x32_bf16(rd_tile(cur, kt * 16 + lrow, 4 + grp), qf1, a, 0, 0, 0);
      s[kt] = a;
    }
    float v[16];
#pragma unroll
    for (int kt = 0; kt < 4; ++kt)
#pragma unroll
      for (int r = 0; r < 4; ++r) v[kt * 4 + r] = s[kt][r] * c;
    float mx = v[0];
#pragma unroll
    for (int i = 1; i < 16; ++i) mx = fmaxf(mx, v[i]);
    float mn = fmaxf(m, mx);
    float sum = 0.f;
#pragma unroll
    for (int i = 0; i < 16; ++i) sum += __builtin_amdgcn_exp2f(v[i] - mn);
    l = l * __builtin_amdgcn_exp2f(m - mn) + sum;
    m = mn;
  }
  // combine 4 lane-groups (k%16 coverage)
#pragma unroll
  for (int d = 16; d <= 32; d <<= 1) {
    float mp = __shfl_xor(m, d), lp = __shfl_xor(l, d);
    float mn = fmaxf(m, mp);
    l = l * __builtin_amdgcn_exp2f(m - mn) + lp * __builtin_amdgcn_exp2f(mp - mn);
    m = mn;
  }
  const float rinv = 1.0f / l;

  // ---- pass B: recompute scores, stage P in LDS, weights + PV ----
  f32x4 cacc[4] = {};
  uint16_t* pw = &Pl[wave][0];
  float* awc = attnw + (((size_t)(b * NHEADS + h)) * SEQ + q0) * SEQ;
#pragma unroll 1
  for (int kc = 0; kc < SEQ / 64; ++kc) {
    __syncthreads();  // previous chunk's Ks/Vs readers done
    stage64(Ks, Kh + (size_t)kc * 64 * D_MODEL, D_MODEL, tid);
    stage64(Vs, Vh + kc * 64, SEQ, tid);
    __syncthreads();
    f32x4 s[4];
#pragma unroll
    for (int kt = 0; kt < 4; ++kt) {
      f32x4 a = {};
      a = __builtin_amdgcn_mfma_f32_16x16x32_bf16(rd_tile(Ks, kt * 16 + lrow, grp),     qf0, a, 0, 0, 0);
      a = __builtin_amdgcn_mfma_f32_16x16x32_bf16(rd_tile(Ks, kt * 16 + lrow, 4 + grp), qf1, a, 0, 0, 0);
      s[kt] = a;
    }
#pragma unroll
    for (int kt = 0; kt < 4; ++kt) {
      ushort4 w;
      w.x = f2bf(__builtin_amdgcn_exp2f(s[kt][0] * c - m) * rinv);
      w.y = f2bf(__builtin_amdgcn_exp2f(s[kt][1] * c - m) * rinv);
      w.z = f2bf(__builtin_amdgcn_exp2f(s[kt][2] * c - m) * rinv);
      w.w = f2bf(__builtin_amdgcn_exp2f(s[kt][3] * c - m) * rinv);
      // P element (q=lrow, k=kt*16+grp*4+j)
      *(ushort4*)&pw[lrow * 72 + kt * 16 + grp * 4] = w;
    }
    asm volatile("s_waitcnt lgkmcnt(0)" ::: "memory");
    // coalesced weight stores: 4 instrs x (4 rows x 256B contiguous)
#pragma unroll
    for (int ii = 0; ii < 4; ++ii) {
      int q = ii * 4 + grp;
      ushort4 t4 = *(const ushort4*)&pw[q * 72 + lrow * 4];
      float4 o = make_float4(bf2f(t4.x), bf2f(t4.y), bf2f(t4.z), bf2f(t4.w));
      *(float4*)&awc[(size_t)q * SEQ + kc * 64 + lrow * 4] = o;
    }
    // PV: acc[q][d] over this 64-key chunk
#pragma unroll
    for (int ks = 0; ks < 2; ++ks) {
      const bf16x8 pf = ldbf8(&pw[lrow * 72 + ks * 32 + grp * 8]);
#pragma unroll
      for (int n = 0; n < 4; ++n) {
        const bf16x8 vf = rd_tile(Vs, n * 16 + lrow, ks * 4 + grp);
        cacc[n] = __builtin_amdgcn_mfma_f32_16x16x32_bf16(pf, vf, cacc[n], 0, 0, 0);
      }
    }
  }
  // ctx: lane holds ctx[q = grp*4+r][d = n*16+lrow]
#pragma unroll
  for (int n = 0; n < 4; ++n)
#pragma unroll
    for (int r = 0; r < 4; ++r) {
      int gq = q0 + grp * 4 + r;
      ctx[((size_t)(b * SEQ) + gq) * D_MODEL + h * HDIM + n * 16 + lrow] = f2bf(cacc[n][r]);
    }
}

// ---------------- launch ----------------
extern "C" void kernel_launch(void* const* d_in, const int* in_sizes, int n_in,
                              void* d_out, int out_size, void* d_ws, size_t ws_size,
                              hipStream_t stream) {
  const float* x  = (const float*)d_in[0];
  const float* wq = (const float*)d_in[1];
  const float* bq = (const float*)d_in[2];
  const float* wk = (const float*)d_in[3];
  const float* bk = (const float*)d_in[4];
  const float* wv = (const float*)d_in[5];
  const float* bv = (const float*)d_in[6];
  const float* wo = (const float*)d_in[7];
  const float* bo = (const float*)d_in[8];

  char* ws = (char*)d_ws;
  uint16_t* xb  = (uint16_t*)ws;                      // 16 MB (reused as ctx later)
  uint16_t* wqb = (uint16_t*)(ws + (16u << 20));
  uint16_t* wkb = (uint16_t*)(ws + (18u << 20));
  uint16_t* wvb = (uint16_t*)(ws + (20u << 20));
  uint16_t* wob = (uint16_t*)(ws + (22u << 20));
  uint16_t* Qb  = (uint16_t*)(ws + (24u << 20));
  uint16_t* Kc  = (uint16_t*)(ws + (40u << 20));
  uint16_t* Vtb = (uint16_t*)(ws + (56u << 20));
  uint16_t* ctx = xb;

  float* outp  = (float*)d_out;
  float* attnw = outp + (size_t)NTOK * D_MODEL;

  {
    int n4 = (NTOK * D_MODEL) / 4;
    cvt_kernel<<<(n4 + 255) / 256, 256, 0, stream>>>(x, xb, n4);
    int w4 = (D_MODEL * D_MODEL) / 4;
    cvt_kernel<<<(w4 + 255) / 256, 256, 0, stream>>>(wq, wqb, w4);
    cvt_kernel<<<(w4 + 255) / 256, 256, 0, stream>>>(wk, wkb, w4);
    cvt_kernel<<<(w4 + 255) / 256, 256, 0, stream>>>(wv, wvb, w4);
    cvt_kernel<<<(w4 + 255) / 256, 256, 0, stream>>>(wo, wob, w4);
  }

  dim3 ggrid(D_MODEL / 128, NTOK / 128);  // (8, 64)
  gemm_bt<0><<<ggrid, 256, 0, stream>>>(xb, wqb, bq, (void*)Qb,  NTOK, D_MODEL, D_MODEL);
  gemm_bt<0><<<ggrid, 256, 0, stream>>>(xb, wkb, bk, (void*)Kc,  NTOK, D_MODEL, D_MODEL);
  gemm_bt<1><<<ggrid, 256, 0, stream>>>(xb, wvb, bv, (void*)Vtb, NTOK, D_MODEL, D_MODEL);

  dim3 agrid(SEQ / 64, NHEADS, BATCH);    // (32, 16, 4)
  attn_kernel<<<agrid, 256, 0, stream>>>(Qb, Kc, Vtb, attnw, ctx);

  gemm_bt<2><<<ggrid, 256, 0, stream>>>(ctx, wob, bo, (void*)outp, NTOK, D_MODEL, D_MODEL);
}

// Round 4
// 462.723 us; speedup vs baseline: 2.3264x; 1.1213x over previous
//
#include <hip/hip_runtime.h>
#include <cstdint>
#include <cstddef>

// MultiHeadSelfAttention: B=4 H=16 S=2048 D=1024 d=64
// d_out = [output fp32 (4,2048,1024)] ++ [attn_weights fp32 (4,16,2048,2048)]
//
// R4: (a) GEMMs use global_load_lds width=16 (m97 structure, linear LDS);
//     (b) attn QBLK=128 (8 waves), pass-B double-buffered, K/V staged via
//         global_load_lds with pre-swizzled global source (LDS linear,
//         XOR-swizzle applied on source + read side).

#define D_MODEL 1024
#define NHEADS  16
#define HDIM    64
#define BATCH   4
#define SEQ     2048
#define NTOK    (BATCH*SEQ)   // 8192

typedef __bf16 bf16x8 __attribute__((ext_vector_type(8)));
typedef float  f32x4  __attribute__((ext_vector_type(4)));
typedef unsigned short u16x8 __attribute__((ext_vector_type(8)));

__device__ __forceinline__ uint16_t f2bf(float f) {
  union { float f; uint32_t u; } v; v.f = f;
  return (uint16_t)((v.u + 0x7FFFu + ((v.u >> 16) & 1u)) >> 16);
}
__device__ __forceinline__ float bf2f(uint16_t u) {
  union { uint32_t u; float f; } v; v.u = (uint32_t)u << 16; return v.f;
}
__device__ __forceinline__ bf16x8 ldbf8(const uint16_t* p) {
  return __builtin_bit_cast(bf16x8, *(const u16x8*)p);
}
// async global->LDS, 16B per lane; lptr must be the wave-uniform base
// (HW writes base + lane*16), gptr is per-lane.
__device__ __forceinline__ void gl_lds16(const uint16_t* g, uint16_t* l) {
  __builtin_amdgcn_global_load_lds(
      (const __attribute__((address_space(1))) uint32_t*)g,
      (__attribute__((address_space(3))) uint32_t*)l, 16, 0, 0);
}

// ---------------- fp32 -> bf16 convert ----------------
__global__ __launch_bounds__(256) void cvt_kernel(const float* __restrict__ src,
                                                  uint16_t* __restrict__ dst, int n4) {
  int i = blockIdx.x * blockDim.x + threadIdx.x;
  if (i < n4) {
    float4 f = ((const float4*)src)[i];
    ushort4 o;
    o.x = f2bf(f.x); o.y = f2bf(f.y); o.z = f2bf(f.z); o.w = f2bf(f.w);
    ((ushort4*)dst)[i] = o;
  }
}

// ---------------- GEMM: out[m,n] = sum_k A[m,k]*Bt[n,k] + bias[n] ----------------
// m97 structure: 128x128 tile, BK=64, linear LDS, global_load_lds width=16,
// 2 barriers per K-step. MODE 0: bf16 [M,N]; 1: bf16 V^T per head; 2: fp32.
template <int MODE>
__global__ __launch_bounds__(256)
void gemm_bt(const uint16_t* __restrict__ A, const uint16_t* __restrict__ Bt,
             const float* __restrict__ bias, void* __restrict__ out,
             int M, int N, int K) {
  __shared__ uint16_t As[128 * 64];
  __shared__ uint16_t Bs[128 * 64];
  const int tid  = threadIdx.x;
  const int lane = tid & 63;
  const int wave = tid >> 6;
  const int wr = wave >> 1, wc = wave & 1;
  const int m0 = blockIdx.y * 128, n0 = blockIdx.x * 128;
  const int lrow = lane & 15;
  const int grp  = lane >> 4;
  const int l8   = lane >> 3;   // sub-row in 1KB chunk
  const int c8   = lane & 7;    // 16B col-block

  f32x4 acc[4][4] = {};

  for (int k0 = 0; k0 < K; k0 += 64) {
#pragma unroll
    for (int it = 0; it < 4; ++it) {
      const int chunk = wave * 4 + it;       // 0..15, 8 rows each
      const int row = chunk * 8 + l8;
      gl_lds16(&A [(size_t)(m0 + row) * K + k0 + c8 * 8], &As[chunk * 512]);
      gl_lds16(&Bt[(size_t)(n0 + row) * K + k0 + c8 * 8], &Bs[chunk * 512]);
    }
    __syncthreads();
#pragma unroll
    for (int ks = 0; ks < 2; ++ks) {
      bf16x8 af[4], bfr[4];
#pragma unroll
      for (int i = 0; i < 4; ++i) {
        af [i] = ldbf8(&As[(wr * 64 + i * 16 + lrow) * 64 + ks * 32 + grp * 8]);
        bfr[i] = ldbf8(&Bs[(wc * 64 + i * 16 + lrow) * 64 + ks * 32 + grp * 8]);
      }
#pragma unroll
      for (int i = 0; i < 4; ++i)
#pragma unroll
        for (int j = 0; j < 4; ++j)
          acc[i][j] = __builtin_amdgcn_mfma_f32_16x16x32_bf16(af[i], bfr[j], acc[i][j], 0, 0, 0);
    }
    __syncthreads();
  }

  const int r0 = grp * 4;
#pragma unroll
  for (int i = 0; i < 4; ++i) {
#pragma unroll
    for (int j = 0; j < 4; ++j) {
      int gmb = m0 + wr * 64 + i * 16 + r0;
      int gn  = n0 + wc * 64 + j * 16 + lrow;
      float bv = bias[gn];
#pragma unroll
      for (int r = 0; r < 4; ++r) {
        float v = acc[i][j][r] + bv;
        int gm = gmb + r;
        if (MODE == 0) {
          ((uint16_t*)out)[(size_t)gm * N + gn] = f2bf(v);
        } else if (MODE == 1) {
          int b = gm >> 11, s = gm & (SEQ - 1);
          int h = gn >> 6,  d = gn & (HDIM - 1);
          ((uint16_t*)out)[(((size_t)(b * NHEADS + h) * HDIM + d) << 11) + s] = f2bf(v);
        } else {
          ((float*)out)[(size_t)gm * N + gn] = v;
        }
      }
    }
  }
}

// ---------------- Attention ----------------
// LDS tile layout: element (row, colblk c in [0,8)) lives at
//   lds[row*64 + (c ^ (row&7))*8 .. +8]   (linear writes via gload_lds with
//   pre-swizzled SOURCE column; read side applies the same XOR)
__device__ __forceinline__ bf16x8 rd_tile(const uint16_t* t, int r, int s) {
  return ldbf8(&t[r * 64 + ((s ^ (r & 7)) * 8)]);
}

#define QBLK 128
// grid (S/128, H, B), 512 thr = 8 waves; wave owns 16 q rows.
// mfma(K,Q): lane holds scores for q=lane&15, k_loc=(lane>>4)*4+r.
__global__ __launch_bounds__(512)
void attn_kernel(const uint16_t* __restrict__ Q, const uint16_t* __restrict__ Kb,
                 const uint16_t* __restrict__ Vt, float* __restrict__ attnw,
                 uint16_t* __restrict__ ctx) {
  __shared__ uint16_t Ks[2][64 * 64];
  __shared__ uint16_t Vs[2][64 * 64];
  __shared__ uint16_t Pl[8][16 * 72];
  const int tid  = threadIdx.x;
  const int lane = tid & 63;
  const int wave = tid >> 6;          // 0..7
  const int qt = blockIdx.x, h = blockIdx.y, b = blockIdx.z;
  const int q0 = qt * QBLK + wave * 16;
  const int lrow = lane & 15;
  const int grp  = lane >> 4;
  const float c = 0.125f * 1.44269504088896f;  // (1/sqrt(64)) * log2(e)

  const uint16_t* Kh = Kb + (size_t)(b * SEQ) * D_MODEL + h * HDIM;   // [s][d] stride 1024
  const uint16_t* Vh = Vt + ((size_t)(b * NHEADS + h) * HDIM) * SEQ;  // [d][s] stride 2048

  const size_t qbase = ((size_t)(b * SEQ) + q0 + lrow) * D_MODEL + h * HDIM;
  const bf16x8 qf0 = ldbf8(&Q[qbase + grp * 8]);
  const bf16x8 qf1 = ldbf8(&Q[qbase + 32 + grp * 8]);

  // per-wave staging coords: wave stages rows [wave*8, wave*8+8) of a 64x64 tile
  const int srow = wave * 8 + (lane >> 3);          // tile row this lane reads
  const int scb  = (lane & 7) ^ (srow & 7);         // pre-swizzled source col-block

  // ---- pass A: online max+sum; K double-buffered ----
  float m = -INFINITY, l = 0.f;
  gl_lds16(&Kh[(size_t)srow * D_MODEL + scb * 8], &Ks[0][wave * 512]);
#pragma unroll 1
  for (int kc = 0; kc < SEQ / 64; ++kc) {
    const int cur = kc & 1;
    __syncthreads();   // staging of cur drained (own-wave vmcnt), prev readers done
    if (kc + 1 < SEQ / 64)
      gl_lds16(&Kh[(size_t)((kc + 1) * 64 + srow) * D_MODEL + scb * 8],
               &Ks[cur ^ 1][wave * 512]);
    const uint16_t* kt_ = Ks[cur];
    f32x4 s[4];
#pragma unroll
    for (int kt = 0; kt < 4; ++kt) {
      f32x4 a = {};
      a = __builtin_amdgcn_mfma_f32_16x16x32_bf16(rd_tile(kt_, kt * 16 + lrow, grp),     qf0, a, 0, 0, 0);
      a = __builtin_amdgcn_mfma_f32_16x16x32_bf16(rd_tile(kt_, kt * 16 + lrow, 4 + grp), qf1, a, 0, 0, 0);
      s[kt] = a;
    }
    float v[16];
#pragma unroll
    for (int kt = 0; kt < 4; ++kt)
#pragma unroll
      for (int r = 0; r < 4; ++r) v[kt * 4 + r] = s[kt][r] * c;
    float mx = v[0];
#pragma unroll
    for (int i = 1; i < 16; ++i) mx = fmaxf(mx, v[i]);
    float mn = fmaxf(m, mx);
    float sum = 0.f;
#pragma unroll
    for (int i = 0; i < 16; ++i) sum += __builtin_amdgcn_exp2f(v[i] - mn);
    l = l * __builtin_amdgcn_exp2f(m - mn) + sum;
    m = mn;
  }
#pragma unroll
  for (int d = 16; d <= 32; d <<= 1) {
    float mp = __shfl_xor(m, d), lp = __shfl_xor(l, d);
    float mn = fmaxf(m, mp);
    l = l * __builtin_amdgcn_exp2f(m - mn) + lp * __builtin_amdgcn_exp2f(mp - mn);
    m = mn;
  }
  const float rinv = 1.0f / l;

  // ---- pass B: recompute scores, weights + PV; K+V double-buffered ----
  f32x4 cacc[4] = {};
  uint16_t* pw = &Pl[wave][0];
  float* awc = attnw + (((size_t)(b * NHEADS + h)) * SEQ + q0) * SEQ;
  gl_lds16(&Kh[(size_t)srow * D_MODEL + scb * 8], &Ks[0][wave * 512]);
  gl_lds16(&Vh[(size_t)srow * SEQ + scb * 8],     &Vs[0][wave * 512]);
#pragma unroll 1
  for (int kc = 0; kc < SEQ / 64; ++kc) {
    const int cur = kc & 1;
    __syncthreads();
    if (kc + 1 < SEQ / 64) {
      gl_lds16(&Kh[(size_t)((kc + 1) * 64 + srow) * D_MODEL + scb * 8],
               &Ks[cur ^ 1][wave * 512]);
      gl_lds16(&Vh[(size_t)srow * SEQ + (kc + 1) * 64 + scb * 8],
               &Vs[cur ^ 1][wave * 512]);
    }
    const uint16_t* kt_ = Ks[cur];
    f32x4 s[4];
#pragma unroll
    for (int kt = 0; kt < 4; ++kt) {
      f32x4 a = {};
      a = __builtin_amdgcn_mfma_f32_16x16x32_bf16(rd_tile(kt_, kt * 16 + lrow, grp),     qf0, a, 0, 0, 0);
      a = __builtin_amdgcn_mfma_f32_16x16x32_bf16(rd_tile(kt_, kt * 16 + lrow, 4 + grp), qf1, a, 0, 0, 0);
      s[kt] = a;
    }
#pragma unroll
    for (int kt = 0; kt < 4; ++kt) {
      ushort4 w;
      w.x = f2bf(__builtin_amdgcn_exp2f(s[kt][0] * c - m) * rinv);
      w.y = f2bf(__builtin_amdgcn_exp2f(s[kt][1] * c - m) * rinv);
      w.z = f2bf(__builtin_amdgcn_exp2f(s[kt][2] * c - m) * rinv);
      w.w = f2bf(__builtin_amdgcn_exp2f(s[kt][3] * c - m) * rinv);
      *(ushort4*)&pw[lrow * 72 + kt * 16 + grp * 4] = w;   // P(q=lrow, k=kt*16+grp*4..)
    }
    asm volatile("s_waitcnt lgkmcnt(0)" ::: "memory");
    // coalesced fp32 weight stores: 4 instrs x (4 q-rows x 256B contiguous)
#pragma unroll
    for (int ii = 0; ii < 4; ++ii) {
      int q = ii * 4 + grp;
      ushort4 t4 = *(const ushort4*)&pw[q * 72 + lrow * 4];
      float4 o = make_float4(bf2f(t4.x), bf2f(t4.y), bf2f(t4.z), bf2f(t4.w));
      *(float4*)&awc[(size_t)q * SEQ + kc * 64 + lrow * 4] = o;
    }
    // PV over this 64-key chunk
    const uint16_t* vt_ = Vs[cur];
#pragma unroll
    for (int ks = 0; ks < 2; ++ks) {
      const bf16x8 pf = ldbf8(&pw[lrow * 72 + ks * 32 + grp * 8]);
#pragma unroll
      for (int n = 0; n < 4; ++n) {
        const bf16x8 vf = rd_tile(vt_, n * 16 + lrow, ks * 4 + grp);
        cacc[n] = __builtin_amdgcn_mfma_f32_16x16x32_bf16(pf, vf, cacc[n], 0, 0, 0);
      }
    }
  }
  // ctx: lane holds ctx[q = grp*4+r][d = n*16+lrow]
#pragma unroll
  for (int n = 0; n < 4; ++n)
#pragma unroll
    for (int r = 0; r < 4; ++r) {
      int gq = q0 + grp * 4 + r;
      ctx[((size_t)(b * SEQ) + gq) * D_MODEL + h * HDIM + n * 16 + lrow] = f2bf(cacc[n][r]);
    }
}

// ---------------- launch ----------------
extern "C" void kernel_launch(void* const* d_in, const int* in_sizes, int n_in,
                              void* d_out, int out_size, void* d_ws, size_t ws_size,
                              hipStream_t stream) {
  const float* x  = (const float*)d_in[0];
  const float* wq = (const float*)d_in[1];
  const float* bq = (const float*)d_in[2];
  const float* wk = (const float*)d_in[3];
  const float* bk = (const float*)d_in[4];
  const float* wv = (const float*)d_in[5];
  const float* bv = (const float*)d_in[6];
  const float* wo = (const float*)d_in[7];
  const float* bo = (const float*)d_in[8];

  char* ws = (char*)d_ws;
  uint16_t* xb  = (uint16_t*)ws;                      // 16 MB (reused as ctx later)
  uint16_t* wqb = (uint16_t*)(ws + (16u << 20));
  uint16_t* wkb = (uint16_t*)(ws + (18u << 20));
  uint16_t* wvb = (uint16_t*)(ws + (20u << 20));
  uint16_t* wob = (uint16_t*)(ws + (22u << 20));
  uint16_t* Qb  = (uint16_t*)(ws + (24u << 20));
  uint16_t* Kc  = (uint16_t*)(ws + (40u << 20));
  uint16_t* Vtb = (uint16_t*)(ws + (56u << 20));
  uint16_t* ctx = xb;

  float* outp  = (float*)d_out;
  float* attnw = outp + (size_t)NTOK * D_MODEL;

  {
    int n4 = (NTOK * D_MODEL) / 4;
    cvt_kernel<<<(n4 + 255) / 256, 256, 0, stream>>>(x, xb, n4);
    int w4 = (D_MODEL * D_MODEL) / 4;
    cvt_kernel<<<(w4 + 255) / 256, 256, 0, stream>>>(wq, wqb, w4);
    cvt_kernel<<<(w4 + 255) / 256, 256, 0, stream>>>(wk, wkb, w4);
    cvt_kernel<<<(w4 + 255) / 256, 256, 0, stream>>>(wv, wvb, w4);
    cvt_kernel<<<(w4 + 255) / 256, 256, 0, stream>>>(wo, wob, w4);
  }

  dim3 ggrid(D_MODEL / 128, NTOK / 128);  // (8, 64)
  gemm_bt<0><<<ggrid, 256, 0, stream>>>(xb, wqb, bq, (void*)Qb,  NTOK, D_MODEL, D_MODEL);
  gemm_bt<0><<<ggrid, 256, 0, stream>>>(xb, wkb, bk, (void*)Kc,  NTOK, D_MODEL, D_MODEL);
  gemm_bt<1><<<ggrid, 256, 0, stream>>>(xb, wvb, bv, (void*)Vtb, NTOK, D_MODEL, D_MODEL);

  dim3 agrid(SEQ / QBLK, NHEADS, BATCH);  // (16, 16, 4)
  attn_kernel<<<agrid, 512, 0, stream>>>(Qb, Kc, Vtb, attnw, ctx);

  gemm_bt<2><<<ggrid, 256, 0, stream>>>(ctx, wob, bo, (void*)outp, NTOK, D_MODEL, D_MODEL);
}